// Round 1
// baseline (1261.533 us; speedup 1.0000x reference)
//
#include <hip/hip_runtime.h>
#include <hip/hip_bf16.h>

// ---------------------------------------------------------------------------
// WindowAttention fused kernel for MI355X (gfx950)
// x[4096,64,192] -> qkv -> 6-head windowed attention (+rel-bias +mask)
// -> softmax (attn is output 1) -> PV -> proj (+bias) (out is output 0)
// One block per window, 6 waves = 1 wave per head. All intermediates in
// LDS/regs; only x read and out/attn written to HBM (plus tiny tables).
// ---------------------------------------------------------------------------

typedef short bf16x8 __attribute__((ext_vector_type(8)));
typedef float f32x4  __attribute__((ext_vector_type(4)));

#define W2_OFF   (576*192*2)                 // bytes
#define BM_OFF   (W2_OFF + 192*192*2)
#define BM_ELEMS (64*6*4*4*64*4)             // [w][h][mt][nt][lane][r] ushort
#define WS_NEEDED ((size_t)BM_OFF + (size_t)BM_ELEMS*2)

static __device__ __forceinline__ unsigned bfr(float x) {   // fp32->bf16 RNE
    unsigned u = __float_as_uint(x);
    return (u + 0x7FFFu + ((u >> 16) & 1u)) >> 16;
}
static __device__ __forceinline__ unsigned pkt(float a, float b) { // trunc pack
    return (__float_as_uint(a) >> 16) | (__float_as_uint(b) & 0xFFFF0000u);
}
static __device__ __forceinline__ float b2f(unsigned short s) {
    return __uint_as_float(((unsigned)s) << 16);
}

// ---------------- prep: weights fp32 -> bf16 -------------------------------
extern "C" __global__ void wa_prep_w(const float* __restrict__ qkv_w,
                                     const float* __restrict__ proj_w,
                                     unsigned short* __restrict__ w1,
                                     unsigned short* __restrict__ w2) {
    const int tot = 576*192 + 192*192;
    for (int i = blockIdx.x * blockDim.x + threadIdx.x; i < tot;
         i += gridDim.x * blockDim.x) {
        if (i < 576*192) w1[i] = (unsigned short)bfr(qkv_w[i]);
        else             w2[i - 576*192] = (unsigned short)bfr(proj_w[i - 576*192]);
    }
}

// ---------------- prep: fused (rel-bias + mask) table, C-layout swizzled ---
extern "C" __global__ void wa_prep_bm(const float* __restrict__ mask,
                                      const float* __restrict__ table,
                                      unsigned short* __restrict__ bm) {
    for (int i = blockIdx.x * blockDim.x + threadIdx.x; i < BM_ELEMS;
         i += gridDim.x * blockDim.x) {
        const int r    = i & 3;
        const int lane = (i >> 2) & 63;
        const int nt   = (i >> 8) & 3;
        const int mt   = (i >> 10) & 3;
        const int wh   = i >> 12;          // w*6 + h
        const int h    = wh % 6;
        const int w    = wh / 6;
        const int quad = lane >> 4, c16 = lane & 15;
        const int ii = mt*16 + quad*4 + r;
        const int jj = nt*16 + c16;
        const int di = (ii >> 3) - (jj >> 3) + 7;
        const int dj = (ii & 7) - (jj & 7) + 7;
        const float v = mask[(w*64 + ii)*64 + jj] + table[(di*15 + dj)*6 + h];
        bm[i] = (unsigned short)bfr(v);
    }
}

// ---------------- main fused kernel ----------------------------------------
extern "C" __global__ __launch_bounds__(384, 3)
void wa_main(const float* __restrict__ x,
             const float* __restrict__ qkv_b,
             const float* __restrict__ proj_b,
             const unsigned short* __restrict__ w1,
             const unsigned short* __restrict__ w2,
             const unsigned short* __restrict__ bm,
             float* __restrict__ out,
             float* __restrict__ attn_out) {
    // LDS map (ushort units). Per wave (head): 6400 ushorts:
    //   q[64][32] @ +0, k[64][32] @ +2048, vT[32][72] @ +4096.
    // P-chunks alias q (ks=0) / k (ks=1) after QK^T (wave-private, DS in-order).
    // ctx[64][200] aliases waves 0-2 region after a barrier.
    __shared__ __align__(16) unsigned short smem[6 * 6400];

    const int tid  = threadIdx.x;
    const int h    = tid >> 6;      // wave id == head
    const int lane = tid & 63;
    const int quad = lane >> 4;
    const int c16  = lane & 15;
    const int b    = blockIdx.x;
    const int wb   = h * 6400;
    const int QB = wb, KB = wb + 2048, VB = wb + 4096;

    // ================= GEMM1: qkv = x @ W1^T + b (this head's 96 cols) =====
    f32x4 accQ[4][2] = {}; f32x4 accK[4][2] = {}; f32x4 accV[4][2] = {};
    #pragma unroll
    for (int ks = 0; ks < 6; ++ks) {
        const int c0 = ks*32 + quad*8;
        bf16x8 xf[4];
        #pragma unroll
        for (int mt = 0; mt < 4; ++mt) {
            const float4* xp =
                (const float4*)(x + ((size_t)b*64 + mt*16 + c16)*192 + c0);
            const float4 a = xp[0], c = xp[1];
            union { bf16x8 v; unsigned u[4]; } uf;
            uf.u[0] = pkt(a.x, a.y); uf.u[1] = pkt(a.z, a.w);
            uf.u[2] = pkt(c.x, c.y); uf.u[3] = pkt(c.z, c.w);
            xf[mt] = uf.v;
        }
        #pragma unroll
        for (int nt = 0; nt < 2; ++nt) {
            const int oq = h*32 + nt*16 + c16;
            const bf16x8 wq = *(const bf16x8*)(w1 + (size_t)oq*192 + c0);
            const bf16x8 wk = *(const bf16x8*)(w1 + (size_t)(oq+192)*192 + c0);
            const bf16x8 wv = *(const bf16x8*)(w1 + (size_t)(oq+384)*192 + c0);
            #pragma unroll
            for (int mt = 0; mt < 4; ++mt) {
                accQ[mt][nt] = __builtin_amdgcn_mfma_f32_16x16x32_bf16(xf[mt], wq, accQ[mt][nt], 0, 0, 0);
                accK[mt][nt] = __builtin_amdgcn_mfma_f32_16x16x32_bf16(xf[mt], wk, accK[mt][nt], 0, 0, 0);
                accV[mt][nt] = __builtin_amdgcn_mfma_f32_16x16x32_bf16(xf[mt], wv, accV[mt][nt], 0, 0, 0);
            }
        }
    }
    // epilogue: +bias (SCALE folded into q), scatter to wave-private LDS
    #pragma unroll
    for (int nt = 0; nt < 2; ++nt) {
        const int oq = h*32 + nt*16 + c16;
        const float bq = qkv_b[oq], bk = qkv_b[oq + 192], bv = qkv_b[oq + 384];
        const int d = nt*16 + c16;
        #pragma unroll
        for (int mt = 0; mt < 4; ++mt) {
            #pragma unroll
            for (int r = 0; r < 4; ++r) {
                const int tok = mt*16 + quad*4 + r;
                smem[QB + tok*32 + d] =
                    (unsigned short)bfr((accQ[mt][nt][r] + bq) * 0.17677669529663687f);
                smem[KB + tok*32 + d] = (unsigned short)bfr(accK[mt][nt][r] + bk);
                smem[VB + d*72 + tok] = (unsigned short)bfr(accV[mt][nt][r] + bv);
            }
        }
    }

    // ================= S = q*scale @ k^T  (K=32, one MFMA k-step) ==========
    bf16x8 qf[4], kf[4];
    #pragma unroll
    for (int t = 0; t < 4; ++t) {
        qf[t] = *(const bf16x8*)&smem[QB + (t*16 + c16)*32 + quad*8];
        kf[t] = *(const bf16x8*)&smem[KB + (t*16 + c16)*32 + quad*8];
    }
    f32x4 s[4][4];
    #pragma unroll
    for (int mt = 0; mt < 4; ++mt)
        #pragma unroll
        for (int nt = 0; nt < 4; ++nt) {
            f32x4 z = {0.f, 0.f, 0.f, 0.f};
            s[mt][nt] = __builtin_amdgcn_mfma_f32_16x16x32_bf16(qf[mt], kf[nt], z, 0, 0, 0);
        }
    // + (rel bias + window mask), pre-swizzled table
    const unsigned short* bmb = bm + ((size_t)(b & 63)*6 + h)*4096;
    #pragma unroll
    for (int mt = 0; mt < 4; ++mt)
        #pragma unroll
        for (int nt = 0; nt < 4; ++nt) {
            const ushort4 bv4 = *(const ushort4*)(bmb + mt*1024 + nt*256 + lane*4);
            s[mt][nt][0] += b2f(bv4.x); s[mt][nt][1] += b2f(bv4.y);
            s[mt][nt][2] += b2f(bv4.z); s[mt][nt][3] += b2f(bv4.w);
        }

    // ================= softmax (rows live in one quad) + attn store ========
    float* aob = attn_out + ((size_t)b*6 + h)*4096;
    #pragma unroll
    for (int mt = 0; mt < 4; ++mt) {
        #pragma unroll
        for (int r = 0; r < 4; ++r) {
            float m0 = fmaxf(fmaxf(s[mt][0][r], s[mt][1][r]),
                             fmaxf(s[mt][2][r], s[mt][3][r]));
            m0 = fmaxf(m0, __shfl_xor(m0, 1, 16));
            m0 = fmaxf(m0, __shfl_xor(m0, 2, 16));
            m0 = fmaxf(m0, __shfl_xor(m0, 4, 16));
            m0 = fmaxf(m0, __shfl_xor(m0, 8, 16));
            float e0 = exp2f((s[mt][0][r] - m0) * 1.4426950408889634f);
            float e1 = exp2f((s[mt][1][r] - m0) * 1.4426950408889634f);
            float e2 = exp2f((s[mt][2][r] - m0) * 1.4426950408889634f);
            float e3 = exp2f((s[mt][3][r] - m0) * 1.4426950408889634f);
            float sum = (e0 + e1) + (e2 + e3);
            sum += __shfl_xor(sum, 1, 16);
            sum += __shfl_xor(sum, 2, 16);
            sum += __shfl_xor(sum, 4, 16);
            sum += __shfl_xor(sum, 8, 16);
            const float rinv = 1.0f / sum;
            e0 *= rinv; e1 *= rinv; e2 *= rinv; e3 *= rinv;
            s[mt][0][r] = e0; s[mt][1][r] = e1; s[mt][2][r] = e2; s[mt][3][r] = e3;
            const int i0 = mt*16 + quad*4 + r;
            aob[i0*64 +  0 + c16] = e0;
            aob[i0*64 + 16 + c16] = e1;
            aob[i0*64 + 32 + c16] = e2;
            aob[i0*64 + 48 + c16] = e3;
        }
    }

    // ================= ctx = P @ V (P via LDS chunks aliasing q/k) =========
    f32x4 accO[4][2] = {};
    #pragma unroll
    for (int ksv = 0; ksv < 2; ++ksv) {
        const int pb = wb + ksv*2048;
        #pragma unroll
        for (int mt = 0; mt < 4; ++mt)
            #pragma unroll
            for (int ntl = 0; ntl < 2; ++ntl)
                #pragma unroll
                for (int r = 0; r < 4; ++r) {
                    const int tok = mt*16 + quad*4 + r;
                    smem[pb + tok*32 + ntl*16 + c16] =
                        (unsigned short)bfr(s[mt][ksv*2 + ntl][r]);
                }
        bf16x8 vf0 = *(const bf16x8*)&smem[VB + c16*72        + ksv*32 + quad*8];
        bf16x8 vf1 = *(const bf16x8*)&smem[VB + (16 + c16)*72 + ksv*32 + quad*8];
        #pragma unroll
        for (int mt = 0; mt < 4; ++mt) {
            const bf16x8 pf = *(const bf16x8*)&smem[pb + (mt*16 + c16)*32 + quad*8];
            accO[mt][0] = __builtin_amdgcn_mfma_f32_16x16x32_bf16(pf, vf0, accO[mt][0], 0, 0, 0);
            accO[mt][1] = __builtin_amdgcn_mfma_f32_16x16x32_bf16(pf, vf1, accO[mt][1], 0, 0, 0);
        }
    }

    // ================= ctx -> shared LDS (cross-wave), then proj ===========
    __syncthreads();                       // all waves done with private bufs
    #pragma unroll
    for (int mt = 0; mt < 4; ++mt)
        #pragma unroll
        for (int ntl = 0; ntl < 2; ++ntl)
            #pragma unroll
            for (int r = 0; r < 4; ++r)
                smem[(mt*16 + quad*4 + r)*200 + h*32 + ntl*16 + c16] =
                    (unsigned short)bfr(accO[mt][ntl][r]);
    __syncthreads();

    f32x4 accU[4][2] = {};
    #pragma unroll
    for (int ks = 0; ks < 6; ++ks) {
        const int c0 = ks*32 + quad*8;
        bf16x8 cf[4];
        #pragma unroll
        for (int mt = 0; mt < 4; ++mt)
            cf[mt] = *(const bf16x8*)&smem[(mt*16 + c16)*200 + c0];
        #pragma unroll
        for (int ntl = 0; ntl < 2; ++ntl) {
            const int o = (h*2 + ntl)*16 + c16;
            const bf16x8 wf = *(const bf16x8*)(w2 + (size_t)o*192 + c0);
            #pragma unroll
            for (int mt = 0; mt < 4; ++mt)
                accU[mt][ntl] = __builtin_amdgcn_mfma_f32_16x16x32_bf16(cf[mt], wf, accU[mt][ntl], 0, 0, 0);
        }
    }
    #pragma unroll
    for (int ntl = 0; ntl < 2; ++ntl) {
        const int o = (h*2 + ntl)*16 + c16;
        const float pb2 = proj_b[o];
        #pragma unroll
        for (int mt = 0; mt < 4; ++mt)
            #pragma unroll
            for (int r = 0; r < 4; ++r)
                out[((size_t)b*64 + mt*16 + quad*4 + r)*192 + o] =
                    accU[mt][ntl][r] + pb2;
    }
}

// ---------------------------------------------------------------------------
extern "C" void kernel_launch(void* const* d_in, const int* in_sizes, int n_in,
                              void* d_out, int out_size, void* d_ws, size_t ws_size,
                              hipStream_t stream) {
    const float* x      = (const float*)d_in[0];
    const float* mask   = (const float*)d_in[1];
    const float* qkv_w  = (const float*)d_in[2];
    const float* qkv_b  = (const float*)d_in[3];
    const float* proj_w = (const float*)d_in[4];
    const float* proj_b = (const float*)d_in[5];
    const float* table  = (const float*)d_in[6];

    if (ws_size < WS_NEEDED) return;   // ~3.5 MB scratch required

    unsigned short* w1 = (unsigned short*)d_ws;
    unsigned short* w2 = (unsigned short*)((char*)d_ws + W2_OFF);
    unsigned short* bm = (unsigned short*)((char*)d_ws + BM_OFF);

    float* out  = (float*)d_out;
    float* attn = out + (size_t)4096 * 64 * 192;

    hipLaunchKernelGGL(wa_prep_w,  dim3(576),  dim3(256), 0, stream,
                       qkv_w, proj_w, w1, w2);
    hipLaunchKernelGGL(wa_prep_bm, dim3(1536), dim3(256), 0, stream,
                       mask, table, bm);
    hipLaunchKernelGGL(wa_main, dim3(4096), dim3(384), 0, stream,
                       x, qkv_b, proj_b, w1, w2, bm, out, attn);
}